// Round 1
// baseline (729.537 us; speedup 1.0000x reference)
//
#include <hip/hip_runtime.h>
#include <stdint.h>

// Problem dims (fixed by reference): B=32,S=1024,D=1024,R=5
#define D_DIM 1024
#define M_DIM 32768   // B*S
#define N_DIM 3072    // 3*D
#define K_DIM 1024    // D
#define R_DIM 5

// 256x256 tile, BK=64, 8 waves (2M x 4N), 8-phase counted-vmcnt schedule (m201-style)
#define BM 256
#define BN 256
#define BK 64
#define NKT (K_DIM / BK)   // 16 K-tiles, 8 iterations of 2

typedef __bf16 bf16x8 __attribute__((ext_vector_type(8)));
typedef float  f32x4  __attribute__((ext_vector_type(4)));
typedef unsigned short ushort8 __attribute__((ext_vector_type(8)));

#define GLOBAL_AS(p) ((const __attribute__((address_space(1))) void*)(p))
#define LDS_AS(p)    ((__attribute__((address_space(3))) void*)(p))

__device__ __forceinline__ unsigned short f2bf(float f) {
    union { float f; unsigned int u; } v; v.f = f;
    unsigned int u = v.u;
    return (unsigned short)((u + 0x7fffu + ((u >> 16) & 1u)) >> 16);
}

// ---------------------------------------------------------------------------
// Kernel 1: Weff[o][c] = bf16( W[o][c] + delta[o][c] )   (unchanged)
// ---------------------------------------------------------------------------
__global__ __launch_bounds__(256) void build_weff_kernel(
    const float* __restrict__ W,
    const float* __restrict__ A0, const float* __restrict__ A1,
    const float* __restrict__ B0, const float* __restrict__ B1,
    const float* __restrict__ s0p, const float* __restrict__ s1p,
    unsigned short* __restrict__ Weff)
{
    int idx = blockIdx.x * blockDim.x + threadIdx.x;
    int o = idx >> 10;
    int c = idx & 1023;
    float w = W[idx];
    if (o >= D_DIM) {
        if (o < 2 * D_DIM) {
            const float* b = B0 + (long)(o - D_DIM) * R_DIM;
            float d = b[0] * A0[c]             + b[1] * A0[D_DIM + c]
                    + b[2] * A0[2 * D_DIM + c] + b[3] * A0[3 * D_DIM + c]
                    + b[4] * A0[4 * D_DIM + c];
            w += s0p[0] * d;
        } else {
            const float* b = B1 + (long)(o - 2 * D_DIM) * R_DIM;
            float d = b[0] * A1[c]             + b[1] * A1[D_DIM + c]
                    + b[2] * A1[2 * D_DIM + c] + b[3] * A1[3 * D_DIM + c]
                    + b[4] * A1[4 * D_DIM + c];
            w += s1p[0] * d;
        }
    }
    Weff[idx] = f2bf(w);
}

// ---------------------------------------------------------------------------
// Kernel 2: x fp32 -> bf16   (unchanged)
// ---------------------------------------------------------------------------
__global__ __launch_bounds__(256) void cvt_x_kernel(
    const float* __restrict__ x, unsigned short* __restrict__ xb)
{
    long idx = (long)blockIdx.x * blockDim.x + threadIdx.x;
    const f32x4* xv = (const f32x4*)x;
    f32x4 a = xv[2 * idx];
    f32x4 b = xv[2 * idx + 1];
    ushort8 r;
    r[0] = f2bf(a[0]); r[1] = f2bf(a[1]); r[2] = f2bf(a[2]); r[3] = f2bf(a[3]);
    r[4] = f2bf(b[0]); r[5] = f2bf(b[1]); r[6] = f2bf(b[2]); r[7] = f2bf(b[3]);
    *(ushort8*)(xb + 8 * idx) = r;
}

// ---------------------------------------------------------------------------
// Kernel 3: C[m][n] = sum_k A[m][k]*Bw[n][k] + bias[n]
// 256x256x64 tile, 8 waves, double-buffered 128 KiB LDS, 4 phases per K-tile
// (8 per iteration), raw s_barrier + counted s_waitcnt vmcnt(8) so stage loads
// stay in flight across barriers. Chunk-XOR LDS swizzle (8 chunks/row):
// slot p of row r holds global chunk p ^ (r&7); reads use the same involution
// -> ds_read_b128 lands 2 lanes/bank (free). global_load_lds dest stays linear
// (wave-uniform base + lane*16); swizzle applied on the global source address.
// ---------------------------------------------------------------------------
__global__ __launch_bounds__(512, 2) void gemm_kernel(
    const unsigned short* __restrict__ A,    // [M][K] bf16 bits
    const unsigned short* __restrict__ Bw,   // [N][K] bf16 bits
    const float* __restrict__ bias,          // [N]
    float* __restrict__ C)                   // [M][N]
{
    __shared__ __align__(16) unsigned short lds[2][2][BM * BK];  // 128 KiB

    const int tid  = threadIdx.x;
    const int lane = tid & 63;
    const int wave = tid >> 6;
    const int wm   = wave >> 2;      // 0..1 : wave's 128-row half
    const int wnq  = wave & 3;       // 0..3 : wave's 64-col quarter
    const int r16  = lane & 15;
    const int quad = lane >> 4;

    // XCD-bijective swizzle (nwg = 1536, divisible by 8) + x-major tile order:
    // each XCD owns 16 contiguous A row-panels; 12 n-tiles per row co-resident.
    const int nwg = (M_DIM / BM) * (N_DIM / BN);   // 1536
    const int cpx = nwg / 8;                        // 192
    int bid = blockIdx.x;
    bid = (bid % 8) * cpx + (bid / 8);
    const int m0 = (bid / (N_DIM / BN)) * BM;
    const int n0 = (bid % (N_DIM / BN)) * BN;

    // --- staging map: LDS elem L = j*4096 + tid*8  ->  row = j*64 + tid/8,
    // slot = tid&7; fetch global chunk = slot ^ (row&7). row&7 == (tid>>3)&7
    // for all j, so chunk is per-thread constant.
    const int jrow  = tid >> 3;                      // 0..63
    const int chunk = (tid & 7) ^ (jrow & 7);
    const unsigned short* aG = A  + (long)(m0 + jrow) * K_DIM + chunk * 8;
    const unsigned short* bG = Bw + (long)(n0 + jrow) * K_DIM + chunk * 8;

#define STAGE(b, t) do {                                                        \
    const unsigned short* _as = aG + (t) * BK;                                  \
    const unsigned short* _bs = bG + (t) * BK;                                  \
    unsigned short* _al = &lds[b][0][0] + tid * 8;                              \
    unsigned short* _bl = &lds[b][1][0] + tid * 8;                              \
    _Pragma("unroll")                                                           \
    for (int j = 0; j < 4; ++j) {                                               \
        __builtin_amdgcn_global_load_lds(GLOBAL_AS(_as + (long)j * 64 * K_DIM), \
                                         LDS_AS(_al + j * 4096), 16, 0, 0);     \
        __builtin_amdgcn_global_load_lds(GLOBAL_AS(_bs + (long)j * 64 * K_DIM), \
                                         LDS_AS(_bl + j * 4096), 16, 0, 0);     \
    }                                                                           \
} while (0)

#define BARRIER() do { asm volatile("" ::: "memory");                 \
                       __builtin_amdgcn_s_barrier();                  \
                       asm volatile("" ::: "memory"); } while (0)
#define VMCNT(n) asm volatile("s_waitcnt vmcnt(" #n ")" ::: "memory")

    // --- fragment read offsets (elements). Row of A-frag mt: wm*128+mt*16+r16;
    // logical chunk kk*4+quad stored at slot ^(row&7); row&7 == r16&7.
    int sA[2];
    sA[0] = ((0 * 4 + quad) ^ (r16 & 7)) * 8;
    sA[1] = ((1 * 4 + quad) ^ (r16 & 7)) * 8;
    const int arowbase = (wm * 128 + r16) * BK;
    const int browbase = (wnq * 64 + r16) * BK;

#define LDA(b, mt, kk) (*(const bf16x8*)(&lds[b][0][0] + arowbase + (mt) * 16 * BK + sA[kk]))
#define LDB(b, nt, kk) (*(const bf16x8*)(&lds[b][1][0] + browbase + (nt) * 16 * BK + sA[kk]))

    bf16x8 af[4][2];   // current m-sub-half: 4 m-frags x 2 k-steps
    bf16x8 bf[4][2];   // all 4 n-frags x 2 k-steps (both n-sub-halves held)
    f32x4  acc[8][4] = {};

#define PHASE_LDA(b, msub)                                  \
    _Pragma("unroll")                                       \
    for (int m = 0; m < 4; ++m) {                           \
        af[m][0] = LDA(b, (msub) * 4 + m, 0);               \
        af[m][1] = LDA(b, (msub) * 4 + m, 1);               \
    }
#define PHASE_LDB(b, nsub)                                  \
    _Pragma("unroll")                                       \
    for (int n = 0; n < 2; ++n) {                           \
        bf[(nsub) * 2 + n][0] = LDB(b, (nsub) * 2 + n, 0);  \
        bf[(nsub) * 2 + n][1] = LDB(b, (nsub) * 2 + n, 1);  \
    }

#define MFMA_QUAD(ms, ns) do {                                                   \
    __builtin_amdgcn_s_setprio(1);                                               \
    _Pragma("unroll")                                                            \
    for (int m = 0; m < 4; ++m)                                                  \
    _Pragma("unroll")                                                            \
    for (int n = 0; n < 2; ++n)                                                  \
    _Pragma("unroll")                                                            \
    for (int kk = 0; kk < 2; ++kk)                                               \
        acc[(ms) * 4 + m][(ns) * 2 + n] = __builtin_amdgcn_mfma_f32_16x16x32_bf16( \
            af[m][kk], bf[(ns) * 2 + n][kk], acc[(ms) * 4 + m][(ns) * 2 + n], 0, 0, 0); \
    __builtin_amdgcn_s_setprio(0);                                               \
} while (0)

    // 4 phases per K-tile. buf reads: B-halves done by P2, A-halves by P3, so
    // the P4 stage-issue into this buffer (post P3-end barrier) cannot clobber.
    // Counted VMCNT(8) leaves the just-issued 8 loads in flight (retired one
    // K-tile later), while guaranteeing the previous batch has landed.
#define KTILE(b, tnext, dostage) do {                       \
    PHASE_LDA(b, 0); PHASE_LDB(b, 0);                       \
    BARRIER(); MFMA_QUAD(0, 0); BARRIER();                  \
    PHASE_LDB(b, 1);                                        \
    BARRIER(); MFMA_QUAD(0, 1); BARRIER();                  \
    PHASE_LDA(b, 1);                                        \
    BARRIER(); MFMA_QUAD(1, 0); BARRIER();                  \
    if (dostage) { STAGE(b, tnext); VMCNT(8); }             \
    else         { VMCNT(0); }                              \
    BARRIER(); MFMA_QUAD(1, 1); BARRIER();                  \
} while (0)

    // prologue: K-tiles 0,1 in flight; wait only for K-tile 0
    STAGE(0, 0);
    STAGE(1, 1);
    VMCNT(8);
    BARRIER();

    for (int i = 0; i < NKT / 2; ++i) {
        const bool st = (i < NKT / 2 - 1);
        KTILE(0, 2 * i + 2, st);
        KTILE(1, 2 * i + 3, st);
    }

    // Epilogue: C/D layout col=lane&15, row=quad*4+reg (m89-verified)
#pragma unroll
    for (int nt = 0; nt < 4; ++nt) {
        const int col = n0 + wnq * 64 + nt * 16 + r16;
        const float bv = bias[col];
#pragma unroll
        for (int mt = 0; mt < 8; ++mt) {
            const long row = m0 + wm * 128 + mt * 16 + quad * 4;
            float* Cp = C + row * (long)N_DIM + col;
#pragma unroll
            for (int r = 0; r < 4; ++r)
                Cp[(long)r * N_DIM] = acc[mt][nt][r] + bv;
        }
    }
}

// ---------------------------------------------------------------------------
extern "C" void kernel_launch(void* const* d_in, const int* in_sizes, int n_in,
                              void* d_out, int out_size, void* d_ws, size_t ws_size,
                              hipStream_t stream) {
    const float* x    = (const float*)d_in[0];   // [32,1024,1024]
    const float* W    = (const float*)d_in[1];   // [3072,1024]
    const float* bias = (const float*)d_in[2];   // [3072]
    const float* A0   = (const float*)d_in[3];   // [5,1024]
    const float* A1   = (const float*)d_in[4];   // [5,1024]
    const float* B0   = (const float*)d_in[5];   // [1024,5]
    const float* B1   = (const float*)d_in[6];   // [1024,5]
    const float* s0   = (const float*)d_in[7];   // scalar
    const float* s1   = (const float*)d_in[8];   // scalar
    float* out = (float*)d_out;                  // [32768,3072] fp32

    unsigned short* Weff = (unsigned short*)d_ws;
    unsigned short* xb   = Weff + (size_t)N_DIM * K_DIM;

    build_weff_kernel<<<(N_DIM * K_DIM) / 256, 256, 0, stream>>>(
        W, A0, A1, B0, B1, s0, s1, Weff);

    cvt_x_kernel<<<((long)M_DIM * K_DIM) / (256 * 8), 256, 0, stream>>>(x, xb);

    dim3 grid((M_DIM / BM) * (N_DIM / BN));   // 1536 blocks, XCD-swizzled in-kernel
    gemm_kernel<<<grid, 512, 0, stream>>>(xb, Weff, bias, out);
}

// Round 2
// 717.464 us; speedup vs baseline: 1.0168x; 1.0168x over previous
//
#include <hip/hip_runtime.h>
#include <stdint.h>

// Problem dims (fixed by reference): B=32,S=1024,D=1024,R=5
#define D_DIM 1024
#define M_DIM 32768   // B*S
#define N_DIM 3072    // 3*D
#define K_DIM 1024    // D
#define R_DIM 5

// 256x256 tile, BK=64, 8 waves (2M x 4N), 8-phase counted-vmcnt schedule
#define BM 256
#define BN 256
#define BK 64
#define NKT (K_DIM / BK)   // 16 K-tiles, 8 iterations of 2

typedef __bf16 bf16x8 __attribute__((ext_vector_type(8)));
typedef float  f32x4  __attribute__((ext_vector_type(4)));
typedef unsigned short ushort8 __attribute__((ext_vector_type(8)));

#define GLOBAL_AS(p) ((const __attribute__((address_space(1))) void*)(p))
#define LDS_AS(p)    ((__attribute__((address_space(3))) void*)(p))

__device__ __forceinline__ unsigned short f2bf(float f) {
    union { float f; unsigned int u; } v; v.f = f;
    unsigned int u = v.u;
    return (unsigned short)((u + 0x7fffu + ((u >> 16) & 1u)) >> 16);
}

// ---------------------------------------------------------------------------
// Kernel 1: Weff[o][c] = bf16( W[o][c] + delta[o][c] )   (unchanged)
// ---------------------------------------------------------------------------
__global__ __launch_bounds__(256) void build_weff_kernel(
    const float* __restrict__ W,
    const float* __restrict__ A0, const float* __restrict__ A1,
    const float* __restrict__ B0, const float* __restrict__ B1,
    const float* __restrict__ s0p, const float* __restrict__ s1p,
    unsigned short* __restrict__ Weff)
{
    int idx = blockIdx.x * blockDim.x + threadIdx.x;
    int o = idx >> 10;
    int c = idx & 1023;
    float w = W[idx];
    if (o >= D_DIM) {
        if (o < 2 * D_DIM) {
            const float* b = B0 + (long)(o - D_DIM) * R_DIM;
            float d = b[0] * A0[c]             + b[1] * A0[D_DIM + c]
                    + b[2] * A0[2 * D_DIM + c] + b[3] * A0[3 * D_DIM + c]
                    + b[4] * A0[4 * D_DIM + c];
            w += s0p[0] * d;
        } else {
            const float* b = B1 + (long)(o - 2 * D_DIM) * R_DIM;
            float d = b[0] * A1[c]             + b[1] * A1[D_DIM + c]
                    + b[2] * A1[2 * D_DIM + c] + b[3] * A1[3 * D_DIM + c]
                    + b[4] * A1[4 * D_DIM + c];
            w += s1p[0] * d;
        }
    }
    Weff[idx] = f2bf(w);
}

// ---------------------------------------------------------------------------
// Kernel 2: x fp32 -> bf16   (unchanged)
// ---------------------------------------------------------------------------
__global__ __launch_bounds__(256) void cvt_x_kernel(
    const float* __restrict__ x, unsigned short* __restrict__ xb)
{
    long idx = (long)blockIdx.x * blockDim.x + threadIdx.x;
    const f32x4* xv = (const f32x4*)x;
    f32x4 a = xv[2 * idx];
    f32x4 b = xv[2 * idx + 1];
    ushort8 r;
    r[0] = f2bf(a[0]); r[1] = f2bf(a[1]); r[2] = f2bf(a[2]); r[3] = f2bf(a[3]);
    r[4] = f2bf(b[0]); r[5] = f2bf(b[1]); r[6] = f2bf(b[2]); r[7] = f2bf(b[3]);
    *(ushort8*)(xb + 8 * idx) = r;
}

// ---------------------------------------------------------------------------
// Kernel 3: C[m][n] = sum_k A[m][k]*Bw[n][k] + bias[n]
// 256x256x64, 8 waves. Per tile-pair (E=buf0, O=buf1), phases P1..P8:
//   P1: reads bf01+af0 of E  | stage O.j2  -> buf1
//   P2: reads bf23 of E      | stage O.j3  -> buf1
//   P3: reads af1 of E       |
//   P4: (no reads)           | stage E2.j0,j1 -> buf0 | MFMA | vmcnt(4)
//   P5..P8: same on O / buf1 | stage E2.j2, E2.j3, -, O2.j0,j1 | vmcnt(4)
// Safety: every ds_read of a phase is consumed by that phase's MFMAs, so by
// each phase-end barrier those LDS reads have retired -> staging into the
// just-read buffer at P4/P8 cannot clobber live reads. vmcnt(4) at P4 leaves
// only E2.j0,j1 in flight => O fully landed before P5's reads (barrier after
// vmcnt publishes across waves). Raw s_barrier + sched_barrier(0) fences:
// NO memory-clobber asm anywhere, so the compiler inserts no vmcnt drains.
// ---------------------------------------------------------------------------
__global__ __launch_bounds__(512, 2) void gemm_kernel(
    const unsigned short* __restrict__ A,    // [M][K] bf16 bits
    const unsigned short* __restrict__ Bw,   // [N][K] bf16 bits
    const float* __restrict__ bias,          // [N]
    float* __restrict__ C)                   // [M][N]
{
    __shared__ __align__(16) unsigned short lds[2][2][BM * BK];  // 128 KiB

    const int tid  = threadIdx.x;
    const int lane = tid & 63;
    const int wave = tid >> 6;
    const int wm   = wave >> 2;      // 0..1 : wave's 128-row half
    const int wnq  = wave & 3;       // 0..3 : wave's 64-col quarter
    const int r16  = lane & 15;
    const int quad = lane >> 4;

    // XCD-bijective swizzle (nwg = 1536, divisible by 8) + x-major tile order
    const int nwg = (M_DIM / BM) * (N_DIM / BN);   // 1536
    const int cpx = nwg / 8;                        // 192
    int bid = blockIdx.x;
    bid = (bid % 8) * cpx + (bid / 8);
    const int m0 = (bid / (N_DIM / BN)) * BM;
    const int n0 = (bid % (N_DIM / BN)) * BN;

    // staging map: LDS elem L = j*4096 + tid*8 -> row = j*64 + tid/8,
    // slot = tid&7; fetch global chunk = slot ^ (row&7)
    const int jrow  = tid >> 3;                      // 0..63
    const int chunk = (tid & 7) ^ (jrow & 7);
    const unsigned short* aG = A  + (long)(m0 + jrow) * K_DIM + chunk * 8;
    const unsigned short* bG = Bw + (long)(n0 + jrow) * K_DIM + chunk * 8;

// stage row-block j (64 rows of A and of B) of K-tile t into buffer b: 2 loads
#define STAGE_J(b, t, j) do {                                                   \
    __builtin_amdgcn_global_load_lds(                                           \
        GLOBAL_AS(aG + (t) * BK + (long)(j) * 64 * K_DIM),                      \
        LDS_AS(&lds[b][0][0] + tid * 8 + (j) * 4096), 16, 0, 0);                \
    __builtin_amdgcn_global_load_lds(                                           \
        GLOBAL_AS(bG + (t) * BK + (long)(j) * 64 * K_DIM),                      \
        LDS_AS(&lds[b][1][0] + tid * 8 + (j) * 4096), 16, 0, 0);                \
} while (0)

#define SCHEDB() __builtin_amdgcn_sched_barrier(0)
#define BAR() do { SCHEDB(); __builtin_amdgcn_s_barrier(); SCHEDB(); } while (0)
#define VMCNT(n) do { SCHEDB(); asm volatile("s_waitcnt vmcnt(" #n ")"); SCHEDB(); } while (0)

    // fragment read offsets (elements); chunk kk*4+quad stored at slot^(row&7)
    int sA[2];
    sA[0] = ((0 * 4 + quad) ^ (r16 & 7)) * 8;
    sA[1] = ((1 * 4 + quad) ^ (r16 & 7)) * 8;
    const int arowbase = (wm * 128 + r16) * BK;
    const int browbase = (wnq * 64 + r16) * BK;

#define LDA(b, mt, kk) (*(const bf16x8*)(&lds[b][0][0] + arowbase + (mt) * 16 * BK + sA[kk]))
#define LDB(b, nt, kk) (*(const bf16x8*)(&lds[b][1][0] + browbase + (nt) * 16 * BK + sA[kk]))

    bf16x8 af[4][2];   // current m-sub-half
    bf16x8 bf[4][2];   // all 4 n-frags
    f32x4  acc[8][4] = {};

#define PHASE_LDA(b, msub)                                  \
    _Pragma("unroll")                                       \
    for (int m = 0; m < 4; ++m) {                           \
        af[m][0] = LDA(b, (msub) * 4 + m, 0);               \
        af[m][1] = LDA(b, (msub) * 4 + m, 1);               \
    }
#define PHASE_LDB(b, nsub)                                  \
    _Pragma("unroll")                                       \
    for (int n = 0; n < 2; ++n) {                           \
        bf[(nsub) * 2 + n][0] = LDB(b, (nsub) * 2 + n, 0);  \
        bf[(nsub) * 2 + n][1] = LDB(b, (nsub) * 2 + n, 1);  \
    }

#define MFMA_QUAD(ms, ns) do {                                                   \
    __builtin_amdgcn_s_setprio(1);                                               \
    _Pragma("unroll")                                                            \
    for (int m = 0; m < 4; ++m)                                                  \
    _Pragma("unroll")                                                            \
    for (int n = 0; n < 2; ++n)                                                  \
    _Pragma("unroll")                                                            \
    for (int kk = 0; kk < 2; ++kk)                                               \
        acc[(ms) * 4 + m][(ns) * 2 + n] = __builtin_amdgcn_mfma_f32_16x16x32_bf16( \
            af[m][kk], bf[(ns) * 2 + n][kk], acc[(ms) * 4 + m][(ns) * 2 + n], 0, 0, 0); \
    __builtin_amdgcn_s_setprio(0);                                               \
} while (0)

    // One K-tile = 4 phases. rb = buffer read this tile.
    // tE: tile whose j2/j3 row-blocks are staged at phases 1,2 (-> buf rb^1)
    // tL: tile whose j0/j1 row-blocks are staged at phase 4 (-> buf rb)
    // vmA: 1 = first-half semantics (else-branch drains to 0 on last iter)
#define HALF(rb, tE, stE, tL, stL, vmA) do {                \
    /* P1 */                                                \
    PHASE_LDB(rb, 0); PHASE_LDA(rb, 0);                     \
    if (stE) STAGE_J((rb) ^ 1, tE, 2);                      \
    BAR(); SCHEDB(); MFMA_QUAD(0, 0); SCHEDB(); BAR();      \
    /* P2 */                                                \
    PHASE_LDB(rb, 1);                                       \
    if (stE) STAGE_J((rb) ^ 1, tE, 3);                      \
    BAR(); SCHEDB(); MFMA_QUAD(0, 1); SCHEDB(); BAR();      \
    /* P3 */                                                \
    PHASE_LDA(rb, 1);                                       \
    BAR(); SCHEDB(); MFMA_QUAD(1, 0); SCHEDB(); BAR();      \
    /* P4 */                                                \
    if (stL) { STAGE_J(rb, tL, 0); STAGE_J(rb, tL, 1); }    \
    BAR(); SCHEDB(); MFMA_QUAD(1, 1); SCHEDB();             \
    if (stL)      { VMCNT(4); }                             \
    else if (vmA) { VMCNT(0); }                             \
    BAR();                                                  \
} while (0)

    // prologue: tile0 fully staged, tile1 j0+j1 in flight
    STAGE_J(0, 0, 0); STAGE_J(0, 0, 1); STAGE_J(0, 0, 2); STAGE_J(0, 0, 3);
    STAGE_J(1, 1, 0); STAGE_J(1, 1, 1);
    VMCNT(4);
    BAR();

#pragma unroll 1
    for (int i = 0; i < NKT / 2; ++i) {
        const bool st = (i < NKT / 2 - 1);
        // half A: read buf0 (tile 2i); stage tile 2i+1 j2,j3 and tile 2i+2 j0,j1
        HALF(0, 2 * i + 1, true, 2 * i + 2, st, 1);
        // half B: read buf1 (tile 2i+1); stage tile 2i+2 j2,j3 and tile 2i+3 j0,j1
        HALF(1, 2 * i + 2, st, 2 * i + 3, st, 0);
    }

    // Epilogue: C/D layout col=lane&15, row=quad*4+reg (m89-verified)
#pragma unroll
    for (int nt = 0; nt < 4; ++nt) {
        const int col = n0 + wnq * 64 + nt * 16 + r16;
        const float bv = bias[col];
#pragma unroll
        for (int mt = 0; mt < 8; ++mt) {
            const long row = m0 + wm * 128 + mt * 16 + quad * 4;
            float* Cp = C + row * (long)N_DIM + col;
#pragma unroll
            for (int r = 0; r < 4; ++r)
                Cp[(long)r * N_DIM] = acc[mt][nt][r] + bv;
        }
    }
}

// ---------------------------------------------------------------------------
extern "C" void kernel_launch(void* const* d_in, const int* in_sizes, int n_in,
                              void* d_out, int out_size, void* d_ws, size_t ws_size,
                              hipStream_t stream) {
    const float* x    = (const float*)d_in[0];   // [32,1024,1024]
    const float* W    = (const float*)d_in[1];   // [3072,1024]
    const float* bias = (const float*)d_in[2];   // [3072]
    const float* A0   = (const float*)d_in[3];   // [5,1024]
    const float* A1   = (const float*)d_in[4];   // [5,1024]
    const float* B0   = (const float*)d_in[5];   // [1024,5]
    const float* B1   = (const float*)d_in[6];   // [1024,5]
    const float* s0   = (const float*)d_in[7];   // scalar
    const float* s1   = (const float*)d_in[8];   // scalar
    float* out = (float*)d_out;                  // [32768,3072] fp32

    unsigned short* Weff = (unsigned short*)d_ws;
    unsigned short* xb   = Weff + (size_t)N_DIM * K_DIM;

    build_weff_kernel<<<(N_DIM * K_DIM) / 256, 256, 0, stream>>>(
        W, A0, A1, B0, B1, s0, s1, Weff);

    cvt_x_kernel<<<((long)M_DIM * K_DIM) / (256 * 8), 256, 0, stream>>>(x, xb);

    dim3 grid((M_DIM / BM) * (N_DIM / BN));   // 1536 blocks, XCD-swizzled in-kernel
    gemm_kernel<<<grid, 512, 0, stream>>>(xb, Weff, bias, out);
}